// Round 12
// baseline (152.226 us; speedup 1.0000x reference)
//
#include <hip/hip_runtime.h>
#include <hip/hip_bf16.h>
#include <stdint.h>

#define NPTS 4096
#define NNBR 16      // neighbors kept (reference keeps 17 incl. self, drops self)
#define PPB  16      // points per block
#define NSEG 128     // candidate segments (seg = t & 127)
#define SEGLEN 32    // candidates per segment
#define SEGPAD 33    // 33 % 32 == 1: lanes' seg-rows hit distinct banks (2-way max)
#define HSTR 132     // heads stride per point (128 seg-minima + pad)
#define CAP  128     // accepted-candidate capacity (top-1 heads: rank(tau) ~ 30-60)
#define TAUM 1.0e-3f // proxy-vs-pinned margin (bound ~4e-5; 25x safety)
#define BIGD 3.4e38f

// ---------------------------------------------------------------------------
// PINNED distance (numpy-order, no contraction) — used ONLY for the accepted
// list's d2 values so the selected neighbor set is bitwise-stable:
//   d2 = (sqp + sqq) - (dot + dot), sqq/sqp = (x*x + y*y) + z*z (pinned)
// ---------------------------------------------------------------------------
__device__ __forceinline__ float sqnorm(float x, float y, float z) {
    return __fadd_rn(__fadd_rn(__fmul_rn(x, x), __fmul_rn(y, y)), __fmul_rn(z, z));
}
__device__ __forceinline__ float d2w(float px, float py, float pz, float sqp,
                                     float cx, float cy, float cz) {
    const float sqq = sqnorm(cx, cy, cz);
    const float dot = __fadd_rn(__fadd_rn(__fmul_rn(px, cx), __fmul_rn(py, cy)),
                                __fmul_rn(pz, cz));
    return __fsub_rn(__fadd_rn(sqp, sqq), __fadd_rn(dot, dot));
}

// CHEAP monotone proxy e = sqq - 2*dot (= d2 - sqp up to ~ulps). SAME macro in
// scan1 and scan2 -> bitwise-identical e for the same candidate; TAUM absorbs
// proxy-vs-pinned cross-space rounding at the acceptance boundary.
#define EVP(PX, PY, PZ, CX, CY, CZ, WW)                                        \
    __builtin_fmaf(__builtin_fmaf(PX, CX, __builtin_fmaf(PY, CY,               \
                   __fmul_rn(PZ, CZ))), -2.0f, WW)
#define SQQ(CX, CY, CZ)                                                        \
    __builtin_fmaf(CZ, CZ, __builtin_fmaf(CY, CY, __fmul_rn(CX, CX)))

// generic K-deep min/max ladder over a register array (static unroll only)
#define LADK(AD, K, S)                                            \
    _Pragma("unroll")                                             \
    for (int k_ = 0; k_ < (K); ++k_) {                            \
        const float lo_ = fminf((S), AD[k_]);                     \
        (S) = fmaxf((S), AD[k_]);                                 \
        AD[k_] = lo_;                                             \
    }

// ---------------------------------------------------------------------------
// Fused exact 16-NN. Block = 512 thr = 4 point-groups x 128 segments (32
// cands each), grid = 1024. Each thread evaluates FOUR points per candidate
// quad: one set of 3 ds_read_b128 feeds 16 evaluations (24 reads/thread/scan
// vs round-11's 128), and sqq is computed once per candidate.
//  scan1 : per-seg MIN of proxy-e per point -> heads[pt][128] (top-1/seg).
//  tau   : 4 thr/pt LAD17 over a 32-value slice (minima of 32 distinct segs
//          = 32 distinct real e-values >= 17 elems => valid subset bound);
//          tau = min of the 4 slice-17ths.
//  scan2 : branchless {e <= tau+TAUM} 32-bit mask per point; extraction
//          appends (PINNED d2, idx) to the per-point list (atomic, CAP=128).
//  final : rank-by-counting (round-11-proven), all 512 threads active.
// No LDS aliasing, all-named scalars (round-8 spill lesson).
// ---------------------------------------------------------------------------
__global__ __launch_bounds__(512, 4) void knn_kernel(const float* __restrict__ x0,
                                                     ushort* __restrict__ nbr) {
    __shared__ float  sx[NSEG * SEGPAD], sy[NSEG * SEGPAD],
                      sz[NSEG * SEGPAD];                     // 3 x 16,896 B
    __shared__ float  heads[PPB * HSTR];                     // 8,448 B
    __shared__ float2 list[PPB * CAP];                       // 16,384 B
    __shared__ float  ttau[PPB][4];
    __shared__ int    cnt[PPB];

    const int b     = blockIdx.x >> 8;       // 256 chunks per batch
    const int chunk = blockIdx.x & 255;
    const float* Xb = x0 + b * (NPTS * 3);
    const int t = threadIdx.x;

    for (int i = t; i < NPTS; i += 512) {
        const int a = (i >> 5) * SEGPAD + (i & 31);
        sx[a] = Xb[3 * i + 0];
        sy[a] = Xb[3 * i + 1];
        sz[a] = Xb[3 * i + 2];
    }
    if (t < PPB) cnt[t] = 0;
    __syncthreads();

    const int pg  = t >> 7;                  // point-group 0..3
    const int seg = t & 127;                 // segment 0..127
    const int p0  = chunk * PPB + pg * 4;    // 4 consecutive batch-local points
    const int a0i = (p0 >> 5) * SEGPAD + (p0 & 31);   // p0..p0+3 same 32-row
    const float px0 = sx[a0i + 0], py0 = sy[a0i + 0], pz0 = sz[a0i + 0];
    const float px1 = sx[a0i + 1], py1 = sy[a0i + 1], pz1 = sz[a0i + 1];
    const float px2 = sx[a0i + 2], py2 = sy[a0i + 2], pz2 = sz[a0i + 2];
    const float px3 = sx[a0i + 3], py3 = sy[a0i + 3], pz3 = sz[a0i + 3];
    const int sb = seg * SEGPAD;

    // ---- scan1: per-seg top-1 of proxy-e for 4 points ----
    float h0 = BIGD, h1 = BIGD, h2 = BIGD, h3 = BIGD;
    for (int j = 0; j < 8; ++j) {
        const int o = sb + 4 * j;
        const float4 cx4 = *(const float4*)&sx[o];
        const float4 cy4 = *(const float4*)&sy[o];
        const float4 cz4 = *(const float4*)&sz[o];
        const float w0 = SQQ(cx4.x, cy4.x, cz4.x);
        const float w1 = SQQ(cx4.y, cy4.y, cz4.y);
        const float w2 = SQQ(cx4.z, cy4.z, cz4.z);
        const float w3 = SQQ(cx4.w, cy4.w, cz4.w);
        h0 = fminf(h0, fminf(fminf(EVP(px0, py0, pz0, cx4.x, cy4.x, cz4.x, w0),
                                   EVP(px0, py0, pz0, cx4.y, cy4.y, cz4.y, w1)),
                             fminf(EVP(px0, py0, pz0, cx4.z, cy4.z, cz4.z, w2),
                                   EVP(px0, py0, pz0, cx4.w, cy4.w, cz4.w, w3))));
        h1 = fminf(h1, fminf(fminf(EVP(px1, py1, pz1, cx4.x, cy4.x, cz4.x, w0),
                                   EVP(px1, py1, pz1, cx4.y, cy4.y, cz4.y, w1)),
                             fminf(EVP(px1, py1, pz1, cx4.z, cy4.z, cz4.z, w2),
                                   EVP(px1, py1, pz1, cx4.w, cy4.w, cz4.w, w3))));
        h2 = fminf(h2, fminf(fminf(EVP(px2, py2, pz2, cx4.x, cy4.x, cz4.x, w0),
                                   EVP(px2, py2, pz2, cx4.y, cy4.y, cz4.y, w1)),
                             fminf(EVP(px2, py2, pz2, cx4.z, cy4.z, cz4.z, w2),
                                   EVP(px2, py2, pz2, cx4.w, cy4.w, cz4.w, w3))));
        h3 = fminf(h3, fminf(fminf(EVP(px3, py3, pz3, cx4.x, cy4.x, cz4.x, w0),
                                   EVP(px3, py3, pz3, cx4.y, cy4.y, cz4.y, w1)),
                             fminf(EVP(px3, py3, pz3, cx4.z, cy4.z, cz4.z, w2),
                                   EVP(px3, py3, pz3, cx4.w, cy4.w, cz4.w, w3))));
    }
    heads[(pg * 4 + 0) * HSTR + seg] = h0;
    heads[(pg * 4 + 1) * HSTR + seg] = h1;
    heads[(pg * 4 + 2) * HSTR + seg] = h2;
    heads[(pg * 4 + 3) * HSTR + seg] = h3;
    __syncthreads();

    // ---- tau: 4 thr/pt, LAD17 over one 32-seg-minima slice (rotated) ----
    if (t < 64) {
        const int pm = t >> 2, qr = t & 3;
        float ad[17];
#pragma unroll
        for (int k = 0; k < 17; ++k) ad[k] = BIGD;
        const int base = pm * HSTR + qr * 32;
        for (int e = 0; e < 32; ++e) {
            float s = heads[base + ((e + t) & 31)];
            LADK(ad, 17, s)
        }
        ttau[pm][qr] = ad[16];               // this slice's 17th-smallest
    }
    __syncthreads();

    // ---- scan2: branchless 32-bit accept masks for 4 points ----
    const int pt0 = pg * 4;
    const float tv0 = fminf(fminf(ttau[pt0 + 0][0], ttau[pt0 + 0][1]),
                            fminf(ttau[pt0 + 0][2], ttau[pt0 + 0][3])) + TAUM;
    const float tv1 = fminf(fminf(ttau[pt0 + 1][0], ttau[pt0 + 1][1]),
                            fminf(ttau[pt0 + 1][2], ttau[pt0 + 1][3])) + TAUM;
    const float tv2 = fminf(fminf(ttau[pt0 + 2][0], ttau[pt0 + 2][1]),
                            fminf(ttau[pt0 + 2][2], ttau[pt0 + 2][3])) + TAUM;
    const float tv3 = fminf(fminf(ttau[pt0 + 3][0], ttau[pt0 + 3][1]),
                            fminf(ttau[pt0 + 3][2], ttau[pt0 + 3][3])) + TAUM;
    uint m0 = 0, m1 = 0, m2 = 0, m3 = 0;
    for (int j = 0; j < 8; ++j) {
        const int o = sb + 4 * j;
        const float4 cx4 = *(const float4*)&sx[o];
        const float4 cy4 = *(const float4*)&sy[o];
        const float4 cz4 = *(const float4*)&sz[o];
        const float w0 = SQQ(cx4.x, cy4.x, cz4.x);
        const float w1 = SQQ(cx4.y, cy4.y, cz4.y);
        const float w2 = SQQ(cx4.z, cy4.z, cz4.z);
        const float w3 = SQQ(cx4.w, cy4.w, cz4.w);
        m0 |= (EVP(px0, py0, pz0, cx4.x, cy4.x, cz4.x, w0) <= tv0) ? (1u << (4 * j + 0)) : 0u;
        m0 |= (EVP(px0, py0, pz0, cx4.y, cy4.y, cz4.y, w1) <= tv0) ? (1u << (4 * j + 1)) : 0u;
        m0 |= (EVP(px0, py0, pz0, cx4.z, cy4.z, cz4.z, w2) <= tv0) ? (1u << (4 * j + 2)) : 0u;
        m0 |= (EVP(px0, py0, pz0, cx4.w, cy4.w, cz4.w, w3) <= tv0) ? (1u << (4 * j + 3)) : 0u;
        m1 |= (EVP(px1, py1, pz1, cx4.x, cy4.x, cz4.x, w0) <= tv1) ? (1u << (4 * j + 0)) : 0u;
        m1 |= (EVP(px1, py1, pz1, cx4.y, cy4.y, cz4.y, w1) <= tv1) ? (1u << (4 * j + 1)) : 0u;
        m1 |= (EVP(px1, py1, pz1, cx4.z, cy4.z, cz4.z, w2) <= tv1) ? (1u << (4 * j + 2)) : 0u;
        m1 |= (EVP(px1, py1, pz1, cx4.w, cy4.w, cz4.w, w3) <= tv1) ? (1u << (4 * j + 3)) : 0u;
        m2 |= (EVP(px2, py2, pz2, cx4.x, cy4.x, cz4.x, w0) <= tv2) ? (1u << (4 * j + 0)) : 0u;
        m2 |= (EVP(px2, py2, pz2, cx4.y, cy4.y, cz4.y, w1) <= tv2) ? (1u << (4 * j + 1)) : 0u;
        m2 |= (EVP(px2, py2, pz2, cx4.z, cy4.z, cz4.z, w2) <= tv2) ? (1u << (4 * j + 2)) : 0u;
        m2 |= (EVP(px2, py2, pz2, cx4.w, cy4.w, cz4.w, w3) <= tv2) ? (1u << (4 * j + 3)) : 0u;
        m3 |= (EVP(px3, py3, pz3, cx4.x, cy4.x, cz4.x, w0) <= tv3) ? (1u << (4 * j + 0)) : 0u;
        m3 |= (EVP(px3, py3, pz3, cx4.y, cy4.y, cz4.y, w1) <= tv3) ? (1u << (4 * j + 1)) : 0u;
        m3 |= (EVP(px3, py3, pz3, cx4.z, cy4.z, cz4.z, w2) <= tv3) ? (1u << (4 * j + 2)) : 0u;
        m3 |= (EVP(px3, py3, pz3, cx4.w, cy4.w, cz4.w, w3) <= tv3) ? (1u << (4 * j + 3)) : 0u;
    }

    // ---- extraction: append (pinned d2, idx); ~0.4 set bits/thread/point ----
    const float sq0 = sqnorm(px0, py0, pz0);
    const float sq1 = sqnorm(px1, py1, pz1);
    const float sq2 = sqnorm(px2, py2, pz2);
    const float sq3 = sqnorm(px3, py3, pz3);
#define EXTRACT(M, PX, PY, PZ, SQ, PTI, PI)                                    \
    while (M) {                                                                \
        const int bpos = __ffs(M) - 1;                                         \
        M &= M - 1;                                                            \
        const int q = seg * SEGLEN + bpos;                                     \
        if (q != (PI)) {                                                       \
            const int qa = (q >> 5) * SEGPAD + (q & 31);                       \
            const float d2 = d2w(PX, PY, PZ, SQ, sx[qa], sy[qa], sz[qa]);      \
            const int o = atomicAdd(&cnt[PTI], 1);                             \
            if (o < CAP) list[(PTI) * CAP + o] = make_float2(d2, __int_as_float(q)); \
        }                                                                      \
    }
    EXTRACT(m0, px0, py0, pz0, sq0, pt0 + 0, p0 + 0)
    EXTRACT(m1, px1, py1, pz1, sq1, pt0 + 1, p0 + 1)
    EXTRACT(m2, px2, py2, pz2, sq2, pt0 + 2, p0 + 2)
    EXTRACT(m3, px3, py3, pz3, sq3, pt0 + 3, p0 + 3)
#undef EXTRACT
    __syncthreads();

    // ---- final: rank-by-counting, all 512 threads (32 slots x 16 points) ----
    {
        const int p2 = t >> 5;               // point 0..15
        const int sl = t & 31;               // slot 0..31
        const int n  = min(cnt[p2], CAP);
        const uint base = (uint)(b * NPTS + chunk * PPB + p2) * (uint)NNBR;
        for (int e = sl; e < n; e += 32) {
            const float2 ve = list[p2 * CAP + e];
            const int ie = __float_as_int(ve.y);
            int r = 0;
            for (int f = 0; f < n; ++f) {
                const float2 vf = list[p2 * CAP + f];
                const bool lt = (vf.x < ve.x) ||
                                (vf.x == ve.x && __float_as_int(vf.y) < ie);
                r += lt ? 1 : 0;
            }
            if (r < NNBR) nbr[base + r] = (ushort)ie;
        }
    }
}

// ---------------------------------------------------------------------------
// MLP + neighbor mean (one wave per point, lane = output channel) with the
// v0 passthrough copy folded in (first 48 blocks copy one float4/thread).
// ---------------------------------------------------------------------------
__global__ __launch_bounds__(256) void mlp_kernel(const float* __restrict__ x0,
                                                  const float* __restrict__ v0,
                                                  const float* __restrict__ W,
                                                  const float* __restrict__ bias,
                                                  const ushort* __restrict__ nbr,
                                                  float* __restrict__ out) {
    const int t   = threadIdx.x;
    const int gid = blockIdx.x * 256 + t;
    if (gid < (4 * NPTS * 3) / 4) {                 // 12288 float4 copies
        ((float4*)(out + 4 * NPTS * 64))[gid] = ((const float4*)v0)[gid];
    }

    const int wave = t >> 6;
    const int lane = t & 63;
    const int gp   = blockIdx.x * 4 + wave;         // global point id 0..16383
    const int b    = gp >> 12;
    const int p    = gp & (NPTS - 1);

    const float* Xb = x0 + b * (NPTS * 3);
    const float* Vb = v0 + b * (NPTS * 3);

    float w[12];
#pragma unroll
    for (int k = 0; k < 12; ++k) w[k] = W[k * 64 + lane];
    const float bb = bias[lane];

    const float xi0 = Xb[p * 3 + 0], xi1 = Xb[p * 3 + 1], xi2 = Xb[p * 3 + 2];
    const float vi0 = Vb[p * 3 + 0], vi1 = Vb[p * 3 + 1], vi2 = Vb[p * 3 + 2];

    const float base = bb + w[0] * xi0 + w[1] * xi1 + w[2] * xi2
                          + w[6] * vi0 + w[7] * vi1 + w[8] * vi2;

    __shared__ float nb[4][NNBR][8];
    if (lane < NNBR) {
        const int j = (int)nbr[(uint)gp * NNBR + lane];
        nb[wave][lane][0] = Xb[j * 3 + 0];
        nb[wave][lane][1] = Xb[j * 3 + 1];
        nb[wave][lane][2] = Xb[j * 3 + 2];
        nb[wave][lane][3] = Vb[j * 3 + 0];
        nb[wave][lane][4] = Vb[j * 3 + 1];
        nb[wave][lane][5] = Vb[j * 3 + 2];
    }
    __syncthreads();

    float acc = 0.0f;
#pragma unroll
    for (int n = 0; n < NNBR; ++n) {
        const float h = base + w[3]  * nb[wave][n][0] + w[4]  * nb[wave][n][1]
                             + w[5]  * nb[wave][n][2] + w[9]  * nb[wave][n][3]
                             + w[10] * nb[wave][n][4] + w[11] * nb[wave][n][5];
        acc += fmaxf(h, 0.0f);
    }

    out[(size_t)gp * 64 + lane] = acc * (1.0f / 16.0f);
}

extern "C" void kernel_launch(void* const* d_in, const int* in_sizes, int n_in,
                              void* d_out, int out_size, void* d_ws, size_t ws_size,
                              hipStream_t stream) {
    const float* x0 = (const float*)d_in[0];   // (4, 12288)
    const float* v0 = (const float*)d_in[1];   // (4, 12288)
    const float* W  = (const float*)d_in[2];   // (12, 64)
    const float* bb = (const float*)d_in[3];   // (64,)
    float* out = (float*)d_out;

    ushort* nbr = (ushort*)d_ws;               // 16384 * 16 * 2B = 512 KB

    // 1) fused exact 16-NN: 1024 blocks (4 batches x 256 chunks of 16 points),
    //    512 threads (4 point-groups x 128 segments).
    knn_kernel<<<1024, 512, 0, stream>>>(x0, nbr);

    // 2) MLP + mean (+ folded v0 copy): 4 points/block, 4096 blocks.
    mlp_kernel<<<4096, 256, 0, stream>>>(x0, v0, W, bb, nbr, out);
}

// Round 15
// 90.514 us; speedup vs baseline: 1.6818x; 1.6818x over previous
//
#include <hip/hip_runtime.h>
#include <hip/hip_bf16.h>
#include <stdint.h>

#define NPTS 4096
#define NNBR 16      // neighbors kept (reference keeps 17 incl. self, drops self)
#define PPB  16      // points per block
#define NSEG 32      // candidate segments (one per t>>4 group)
#define SEGLEN 128   // candidates per segment
#define SEGPAD 132   // 132 % 32 == 4: the 4 segs in a wave land on bank-quads 0/4/8/12
#define HSTR2 193    // heads stride per point (192 kept keys + pad, odd)
#define CAP  96      // accepted capacity (rank(cut) ~ 40-55, R11-proven headroom)
#define BIAS 64.0f   // key bias: ek = e + 64 > 0 always (e >= -sqp >= -40)
#define TRMASK 0xFFFFFF80u  // zero low 7 mantissa bits for the index
#define PMARG 1.0e-2f
// PMARG proof: |packed-(e_pin+64)| <= d = trunc(<=2e-3 at ek<256) + proxy(~1e-5).
// 17 cands have packed <= tau_p => e_pin(17th) <= tau_p-64+d. True NN c* has
// e_pin(c*) <= e_pin(17th) => packed(c*) <= tau_p+2d <= tau_p+PMARG. [2d<5e-3]
#define BIGD 3.4e38f

// ---------------------------------------------------------------------------
// PINNED distance (numpy-order, no contraction) — used ONLY for the accepted
// list's d2 values so the selected neighbor set is bitwise-stable.
// ---------------------------------------------------------------------------
__device__ __forceinline__ float sqnorm(float x, float y, float z) {
    return __fadd_rn(__fadd_rn(__fmul_rn(x, x), __fmul_rn(y, y)), __fmul_rn(z, z));
}
__device__ __forceinline__ float d2w(float px, float py, float pz, float sqp,
                                     float cx, float cy, float cz, float sqq) {
    const float dot = __fadd_rn(__fadd_rn(__fmul_rn(px, cx), __fmul_rn(py, cy)),
                                __fmul_rn(pz, cz));
    return __fsub_rn(__fadd_rn(sqp, sqq), __fadd_rn(dot, dot));
}
// Cheap proxy e = sqq - 2*dot; packed key = trunc7(bits(e+64)) | local_idx.
// ONE macro used in scan AND fallback rescan -> identical bits per candidate.
#define PACKKEY(DST, PX, PY, PZ, CX, CY, CZ, WW, LI)                           \
    {                                                                          \
        const float dot_ = __builtin_fmaf(PX, CX,                              \
                            __builtin_fmaf(PY, CY, __fmul_rn(PZ, CZ)));        \
        const float ek_  = __builtin_fmaf(dot_, -2.0f, WW) + BIAS;             \
        DST = __uint_as_float((__float_as_uint(ek_) & TRMASK) | (uint)(LI));   \
    }

// generic K-deep min/max ladder over a register array (static unroll only)
#define LADK(AD, K, S)                                            \
    _Pragma("unroll")                                             \
    for (int k_ = 0; k_ < (K); ++k_) {                            \
        const float lo_ = fminf((S), AD[k_]);                     \
        (S) = fmaxf((S), AD[k_]);                                 \
        AD[k_] = lo_;                                             \
    }

// ---------------------------------------------------------------------------
// Fused exact 16-NN, single-scan packed-key version (R14 + quad-watermark fix).
// Block = 512 thr = 16 points x 32 segments, grid = 1024 (1 pt/thread —
// multi-pt variants spill to scratch: R8/R12 lesson).
//  scan : per quad pack 4 keys -> top-2 tree (tracking dmin = min over quads
//         of the quad's 3rd-smallest, the discard watermark) -> exact
//         order-stat merge into sorted keep-6. 128 ds_read_b128/thread.
//  tau  : heads[pt][192]; 2 thr/pt LAD17 over a 96-key half (covers 16 segs);
//         cut = min(two half-17ths) + PMARG.
//  extr : fast path REQUIRES k5 > cut AND dmin > cut (R14 bug: quad-level
//         discards could be <= cut while k5 > cut -> missed true neighbors).
//         Merge evictions >= final k5; quad discards >= dmin -> with both
//         guards, every candidate <= cut is among k0..k4. Else exact rescan.
//  final: pinned-d2 rank-by-counting (round-11-proven) -> identical sets.
// ---------------------------------------------------------------------------
__global__ __launch_bounds__(512, 4) void knn_kernel(const float* __restrict__ x0,
                                                     ushort* __restrict__ nbr) {
    __shared__ float sx[NSEG * SEGPAD], sy[NSEG * SEGPAD],
                     sz[NSEG * SEGPAD], sw[NSEG * SEGPAD];   // 4 x 16,896 B
    __shared__ __align__(16) float ubuf[PPB * HSTR2];        // 12,352 B
    __shared__ float ttau[PPB][2];
    __shared__ int   cnt[PPB];

    float*  heads = ubuf;                    // live: scan -> tau
    float2* list  = (float2*)ubuf;           // live: extraction -> final (12,288 B)

    const int b     = blockIdx.x >> 8;       // 256 chunks per batch
    const int chunk = blockIdx.x & 255;
    const float* Xb = x0 + b * (NPTS * 3);
    const int t = threadIdx.x;

    for (int i = t; i < NPTS; i += 512) {
        const int a = (i >> 7) * SEGPAD + (i & 127);
        const float x = Xb[3 * i + 0];
        const float y = Xb[3 * i + 1];
        const float z = Xb[3 * i + 2];
        sx[a] = x; sy[a] = y; sz[a] = z; sw[a] = sqnorm(x, y, z);
    }
    if (t < PPB) cnt[t] = 0;
    __syncthreads();

    const int pt = t & 15, seg = t >> 4;     // seg 0..31
    const int p  = chunk * PPB + pt;         // batch-local point id
    const int pa = (p >> 7) * SEGPAD + (p & 127);
    const float px = sx[pa], py = sy[pa], pz = sz[pa], sqp = sw[pa];
    const int sb = seg * SEGPAD;

    // ---- scan: sorted keep-6 of packed keys + discard watermark dmin ----
    float k0 = BIGD, k1 = BIGD, k2 = BIGD, k3 = BIGD, k4 = BIGD, k5 = BIGD;
    float dmin = BIGD;                       // min over quads of quad-3rd-smallest
    for (int j = 0; j < 32; ++j) {
        const int o = sb + 4 * j;
        const float4 cx4 = *(const float4*)&sx[o];
        const float4 cy4 = *(const float4*)&sy[o];
        const float4 cz4 = *(const float4*)&sz[o];
        const float4 cw4 = *(const float4*)&sw[o];
        float p0, p1, p2, p3;
        PACKKEY(p0, px, py, pz, cx4.x, cy4.x, cz4.x, cw4.x, 4 * j + 0)
        PACKKEY(p1, px, py, pz, cx4.y, cy4.y, cz4.y, cw4.y, 4 * j + 1)
        PACKKEY(p2, px, py, pz, cx4.z, cy4.z, cz4.z, cw4.z, 4 * j + 2)
        PACKKEY(p3, px, py, pz, cx4.w, cy4.w, cz4.w, cw4.w, 4 * j + 3)
        // sorted-4 tree: b0 <= b1 kept, b2 = 3rd smallest (discard watermark)
        const float q01 = fminf(p0, p1), Q01 = fmaxf(p0, p1);
        const float q23 = fminf(p2, p3), Q23 = fmaxf(p2, p3);
        const float hi_mins = fmaxf(q01, q23);
        const float lo_maxs = fminf(Q01, Q23);
        const float b0 = fminf(q01, q23);
        const float b1 = fminf(hi_mins, lo_maxs);
        const float b2 = fmaxf(hi_mins, lo_maxs);
        dmin = fminf(dmin, b2);
        // exact merge of sorted-6 with sorted-2, keep smallest 6:
        // m[i] = min(a[i], max(a[i-1],b0), max(a[i-2],b1))
        const float n0 = fminf(k0, b0);
        const float n1 = fminf(k1, fminf(fmaxf(k0, b0), b1));
        const float n2 = fminf(k2, fminf(fmaxf(k1, b0), fmaxf(k0, b1)));
        const float n3 = fminf(k3, fminf(fmaxf(k2, b0), fmaxf(k1, b1)));
        const float n4 = fminf(k4, fminf(fmaxf(k3, b0), fmaxf(k2, b1)));
        const float n5 = fminf(k5, fminf(fmaxf(k4, b0), fmaxf(k3, b1)));
        k0 = n0; k1 = n1; k2 = n2; k3 = n3; k4 = n4; k5 = n5;
    }
    {
        float* hd = heads + pt * HSTR2 + seg * 6;
        hd[0] = k0; hd[1] = k1; hd[2] = k2; hd[3] = k3; hd[4] = k4; hd[5] = k5;
    }
    __syncthreads();

    // ---- tau: 2 thr/pt, LAD17 over one 96-key half (covers 16 segments) ----
    if (t < 32) {
        const int pm = t >> 1, half = t & 1;
        float ad[17];
#pragma unroll
        for (int k = 0; k < 17; ++k) ad[k] = BIGD;
        const float* src = heads + pm * HSTR2 + half * 96;
        for (int e = 0; e < 96; ++e) {
            float s = src[e];
            LADK(ad, 17, s)
        }
        ttau[pm][half] = ad[16];             // this half's 17th-smallest
    }
    __syncthreads();                         // heads dead; list reuses ubuf

    // ---- extraction: fast path needs k5 > cut AND dmin > cut ----
    const float cut = fminf(ttau[pt][0], ttau[pt][1]) + PMARG;
#define APPENDK(KV)                                                            \
    if ((KV) <= cut) {                                                         \
        const int q = seg * SEGLEN + (int)(__float_as_uint(KV) & 0x7Fu);       \
        if (q != p) {                                                          \
            const int qa = (q >> 7) * SEGPAD + (q & 127);                      \
            const float d2 = d2w(px, py, pz, sqp, sx[qa], sy[qa], sz[qa], sw[qa]); \
            const int o = atomicAdd(&cnt[pt], 1);                              \
            if (o < CAP) list[pt * CAP + o] = make_float2(d2, __int_as_float(q)); \
        }                                                                      \
    }
    if (k5 > cut && dmin > cut) {            // all accepted are among k0..k4
        APPENDK(k0) APPENDK(k1) APPENDK(k2)
        APPENDK(k3) APPENDK(k4)              // k5 > cut by the branch
    } else {                                 // rare: a discard may be <= cut
        for (int j = 0; j < 32; ++j) {
            const int o = sb + 4 * j;
            const float4 cx4 = *(const float4*)&sx[o];
            const float4 cy4 = *(const float4*)&sy[o];
            const float4 cz4 = *(const float4*)&sz[o];
            const float4 cw4 = *(const float4*)&sw[o];
            float p0, p1, p2, p3;
            PACKKEY(p0, px, py, pz, cx4.x, cy4.x, cz4.x, cw4.x, 4 * j + 0)
            PACKKEY(p1, px, py, pz, cx4.y, cy4.y, cz4.y, cw4.y, 4 * j + 1)
            PACKKEY(p2, px, py, pz, cx4.z, cy4.z, cz4.z, cw4.z, 4 * j + 2)
            PACKKEY(p3, px, py, pz, cx4.w, cy4.w, cz4.w, cw4.w, 4 * j + 3)
            APPENDK(p0) APPENDK(p1) APPENDK(p2) APPENDK(p3)
        }
    }
#undef APPENDK
    __syncthreads();

    // ---- final: rank-by-counting, all 512 threads (32 slots x 16 points) ----
    {
        const int p2 = t >> 5;               // point 0..15
        const int sl = t & 31;               // slot 0..31
        const int n  = min(cnt[p2], CAP);
        const uint base = (uint)(b * NPTS + chunk * PPB + p2) * (uint)NNBR;
        for (int e = sl; e < n; e += 32) {
            const float2 ve = list[p2 * CAP + e];
            const int ie = __float_as_int(ve.y);
            int r = 0;
            for (int f = 0; f < n; ++f) {
                const float2 vf = list[p2 * CAP + f];
                const bool lt = (vf.x < ve.x) ||
                                (vf.x == ve.x && __float_as_int(vf.y) < ie);
                r += lt ? 1 : 0;
            }
            if (r < NNBR) nbr[base + r] = (ushort)ie;
        }
    }
}

// ---------------------------------------------------------------------------
// MLP + neighbor mean (one wave per point, lane = output channel) with the
// v0 passthrough copy folded in (first 48 blocks copy one float4/thread).
// ---------------------------------------------------------------------------
__global__ __launch_bounds__(256) void mlp_kernel(const float* __restrict__ x0,
                                                  const float* __restrict__ v0,
                                                  const float* __restrict__ W,
                                                  const float* __restrict__ bias,
                                                  const ushort* __restrict__ nbr,
                                                  float* __restrict__ out) {
    const int t   = threadIdx.x;
    const int gid = blockIdx.x * 256 + t;
    if (gid < (4 * NPTS * 3) / 4) {                 // 12288 float4 copies
        ((float4*)(out + 4 * NPTS * 64))[gid] = ((const float4*)v0)[gid];
    }

    const int wave = t >> 6;
    const int lane = t & 63;
    const int gp   = blockIdx.x * 4 + wave;         // global point id 0..16383
    const int b    = gp >> 12;
    const int p    = gp & (NPTS - 1);

    const float* Xb = x0 + b * (NPTS * 3);
    const float* Vb = v0 + b * (NPTS * 3);

    float w[12];
#pragma unroll
    for (int k = 0; k < 12; ++k) w[k] = W[k * 64 + lane];
    const float bb = bias[lane];

    const float xi0 = Xb[p * 3 + 0], xi1 = Xb[p * 3 + 1], xi2 = Xb[p * 3 + 2];
    const float vi0 = Vb[p * 3 + 0], vi1 = Vb[p * 3 + 1], vi2 = Vb[p * 3 + 2];

    const float base = bb + w[0] * xi0 + w[1] * xi1 + w[2] * xi2
                          + w[6] * vi0 + w[7] * vi1 + w[8] * vi2;

    __shared__ float nb[4][NNBR][8];
    if (lane < NNBR) {
        const int j = (int)nbr[(uint)gp * NNBR + lane];
        nb[wave][lane][0] = Xb[j * 3 + 0];
        nb[wave][lane][1] = Xb[j * 3 + 1];
        nb[wave][lane][2] = Xb[j * 3 + 2];
        nb[wave][lane][3] = Vb[j * 3 + 0];
        nb[wave][lane][4] = Vb[j * 3 + 1];
        nb[wave][lane][5] = Vb[j * 3 + 2];
    }
    __syncthreads();

    float acc = 0.0f;
#pragma unroll
    for (int n = 0; n < NNBR; ++n) {
        const float h = base + w[3]  * nb[wave][n][0] + w[4]  * nb[wave][n][1]
                             + w[5]  * nb[wave][n][2] + w[9]  * nb[wave][n][3]
                             + w[10] * nb[wave][n][4] + w[11] * nb[wave][n][5];
        acc += fmaxf(h, 0.0f);
    }

    out[(size_t)gp * 64 + lane] = acc * (1.0f / 16.0f);
}

extern "C" void kernel_launch(void* const* d_in, const int* in_sizes, int n_in,
                              void* d_out, int out_size, void* d_ws, size_t ws_size,
                              hipStream_t stream) {
    const float* x0 = (const float*)d_in[0];   // (4, 12288)
    const float* v0 = (const float*)d_in[1];   // (4, 12288)
    const float* W  = (const float*)d_in[2];   // (12, 64)
    const float* bb = (const float*)d_in[3];   // (64,)
    float* out = (float*)d_out;

    ushort* nbr = (ushort*)d_ws;               // 16384 * 16 * 2B = 512 KB

    // 1) fused exact 16-NN: 1024 blocks (4 batches x 256 chunks of 16 points),
    //    512 threads (16 pts x 32 segs), single packed-key scan.
    knn_kernel<<<1024, 512, 0, stream>>>(x0, nbr);

    // 2) MLP + mean (+ folded v0 copy): 4 points/block, 4096 blocks.
    mlp_kernel<<<4096, 256, 0, stream>>>(x0, v0, W, bb, nbr, out);
}

// Round 16
// 61.129 us; speedup vs baseline: 2.4903x; 1.4807x over previous
//
#include <hip/hip_runtime.h>
#include <hip/hip_bf16.h>
#include <stdint.h>

#define NPTS 4096
#define NNBR 16      // neighbors kept (reference keeps 17 incl. self, drops self)
#define PPB  16      // points per block
#define NSEG 32      // candidate segments (one per t>>4 group)
#define SEGLEN 128   // candidates per segment
#define SEGPAD 132   // 132 % 32 == 4: the 4 segs in a wave land on bank-quads 0/4/8/12
#define HSTR 33      // heads stride per point (32 seg-minima + pad)
#define CAP  96      // accepted capacity (rank(tau) ~ 35-45, headroom ~2x)
#define TAUM 1.0e-3f // proxy-vs-pinned margin (bound ~4e-5; 25x safety)
#define BIGD 3.4e38f

// ---------------------------------------------------------------------------
// PINNED distance (numpy-order, no contraction) — used for the accepted-list
// d2 values so the selected neighbor set is bitwise-stable:
//   d2 = (sqp + sqq) - (dot + dot), sqq staged in sw with pinned sqnorm bits.
// ---------------------------------------------------------------------------
__device__ __forceinline__ float sqnorm(float x, float y, float z) {
    return __fadd_rn(__fadd_rn(__fmul_rn(x, x), __fmul_rn(y, y)), __fmul_rn(z, z));
}
__device__ __forceinline__ float d2w(float px, float py, float pz, float sqp,
                                     float cx, float cy, float cz, float sqq) {
    const float dot = __fadd_rn(__fadd_rn(__fmul_rn(px, cx), __fmul_rn(py, cy)),
                                __fmul_rn(pz, cz));
    return __fsub_rn(__fadd_rn(sqp, sqq), __fadd_rn(dot, dot));
}
// CHEAP monotone proxy for the scans: e = sqq - 2*dot (= d2 - sqp up to ~ulps).
// TAUM margin in scan2 absorbs all proxy-vs-pinned rounding differences.
__device__ __forceinline__ float eproxy(float px, float py, float pz,
                                        float cx, float cy, float cz, float sqq) {
    const float dot = __builtin_fmaf(px, cx, __builtin_fmaf(py, cy, __fmul_rn(pz, cz)));
    return __builtin_fmaf(dot, -2.0f, sqq);
}

// generic K-deep min/max ladder over a register array (static unroll only)
#define LADK(AD, K, S)                                            \
    _Pragma("unroll")                                             \
    for (int k_ = 0; k_ < (K); ++k_) {                            \
        const float lo_ = fminf((S), AD[k_]);                     \
        (S) = fmaxf((S), AD[k_]);                                 \
        AD[k_] = lo_;                                             \
    }

// ---------------------------------------------------------------------------
// Fused exact 16-NN. Block = 512 thr = 16 points x 32 segments, grid = 1024.
// R11 structure (proven 66us knn / absmax 0.0546875) with ONE delta:
//  scan1 keeps only the per-seg MINIMUM of proxy-e (dual independent chains,
//  4 VALU/quad vs TOP2MERGE's 12). tau = 17th-smallest of the 32 seg-minima
//  (32 distinct real e-values >= 17 elems => valid subset order-stat bound;
//  rank(tau) ~ 35-45 since the top-17 NN occupy ~13 distinct segments).
//  scan2 / extraction / pinned-d2 rank-by-counting final: byte-identical
//  to R11 => identical neighbor sets.
// 1 pt/thread (multi-pt variants spill to scratch: R8/R12 lesson).
// ---------------------------------------------------------------------------
__global__ __launch_bounds__(512, 4) void knn_kernel(const float* __restrict__ x0,
                                                     ushort* __restrict__ nbr) {
    __shared__ float sx[NSEG * SEGPAD], sy[NSEG * SEGPAD],
                     sz[NSEG * SEGPAD], sw[NSEG * SEGPAD];   // 4 x 16,896 B
    __shared__ float2 list[PPB * CAP];                       // 12,288 B
    __shared__ float ttau[PPB];
    __shared__ int   cnt[PPB];

    float* heads = (float*)list;             // alias: heads dead before extraction

    const int b     = blockIdx.x >> 8;       // 256 chunks per batch
    const int chunk = blockIdx.x & 255;
    const float* Xb = x0 + b * (NPTS * 3);
    const int t = threadIdx.x;

    for (int i = t; i < NPTS; i += 512) {
        const int a = (i >> 7) * SEGPAD + (i & 127);
        const float x = Xb[3 * i + 0];
        const float y = Xb[3 * i + 1];
        const float z = Xb[3 * i + 2];
        sx[a] = x; sy[a] = y; sz[a] = z; sw[a] = sqnorm(x, y, z);
    }
    if (t < PPB) cnt[t] = 0;
    __syncthreads();

    const int pt = t & 15, seg = t >> 4;     // seg 0..31
    const int p  = chunk * PPB + pt;         // batch-local point id
    const int pa = (p >> 7) * SEGPAD + (p & 127);
    const float px = sx[pa], py = sy[pa], pz = sz[pa], sqp = sw[pa];
    const int sb = seg * SEGPAD;

    // ---- scan1: per-seg MIN of proxy-e, dual independent chains ----
    float ha = BIGD, hb = BIGD;
    for (int j = 0; j < 32; j += 2) {
        const int oa = sb + 4 * j;
        const int ob = oa + 4;
        const float4 cxa = *(const float4*)&sx[oa];
        const float4 cya = *(const float4*)&sy[oa];
        const float4 cza = *(const float4*)&sz[oa];
        const float4 cwa = *(const float4*)&sw[oa];
        const float4 cxb = *(const float4*)&sx[ob];
        const float4 cyb = *(const float4*)&sy[ob];
        const float4 czb = *(const float4*)&sz[ob];
        const float4 cwb = *(const float4*)&sw[ob];
        const float sa0 = eproxy(px, py, pz, cxa.x, cya.x, cza.x, cwa.x);
        const float sa1 = eproxy(px, py, pz, cxa.y, cya.y, cza.y, cwa.y);
        const float sa2 = eproxy(px, py, pz, cxa.z, cya.z, cza.z, cwa.z);
        const float sa3 = eproxy(px, py, pz, cxa.w, cya.w, cza.w, cwa.w);
        const float sb0 = eproxy(px, py, pz, cxb.x, cyb.x, czb.x, cwb.x);
        const float sb1 = eproxy(px, py, pz, cxb.y, cyb.y, czb.y, cwb.y);
        const float sb2 = eproxy(px, py, pz, cxb.z, cyb.z, czb.z, cwb.z);
        const float sb3 = eproxy(px, py, pz, cxb.w, cyb.w, czb.w, cwb.w);
        ha = fminf(ha, fminf(fminf(sa0, sa1), fminf(sa2, sa3)));
        hb = fminf(hb, fminf(fminf(sb0, sb1), fminf(sb2, sb3)));
    }
    heads[pt * HSTR + seg] = fminf(ha, hb);  // this segment's minimum
    __syncthreads();

    // ---- tau: 1 thr/pt, LAD17 over the 32 seg-minima (rotated reads) ----
    if (t < PPB) {
        float ad[17];
#pragma unroll
        for (int k = 0; k < 17; ++k) ad[k] = BIGD;
        const float* src = heads + t * HSTR;
        for (int e = 0; e < 32; ++e) {
            float s = src[(e + t) & 31];
            LADK(ad, 17, s)
        }
        ttau[t] = ad[16];                    // 17th-smallest seg-minimum
    }
    __syncthreads();                         // heads dead; list reuses the space

    // ---- scan2: branchless accept-bitmask per 32-cand word + extraction ----
    const float tv = ttau[pt] + TAUM;
    for (int w = 0; w < 4; ++w) {
        uint m = 0;
#pragma unroll
        for (int jj = 0; jj < 8; ++jj) {
            const int o = sb + w * 32 + 4 * jj;
            const float4 cx4 = *(const float4*)&sx[o];
            const float4 cy4 = *(const float4*)&sy[o];
            const float4 cz4 = *(const float4*)&sz[o];
            const float4 cw4 = *(const float4*)&sw[o];
            const float s0 = eproxy(px, py, pz, cx4.x, cy4.x, cz4.x, cw4.x);
            const float s1 = eproxy(px, py, pz, cx4.y, cy4.y, cz4.y, cw4.y);
            const float s2 = eproxy(px, py, pz, cx4.z, cy4.z, cz4.z, cw4.z);
            const float s3 = eproxy(px, py, pz, cx4.w, cy4.w, cz4.w, cw4.w);
            m |= (s0 <= tv) ? (1u << (4 * jj + 0)) : 0u;
            m |= (s1 <= tv) ? (1u << (4 * jj + 1)) : 0u;
            m |= (s2 <= tv) ? (1u << (4 * jj + 2)) : 0u;
            m |= (s3 <= tv) ? (1u << (4 * jj + 3)) : 0u;
        }
        while (m) {                          // ~1-2 set bits/thread total
            const int bpos = __ffs(m) - 1;
            m &= m - 1;
            const int q = seg * SEGLEN + w * 32 + bpos;   // batch-local cand id
            if (q != p) {
                const int qa = (q >> 7) * SEGPAD + (q & 127);
                const float d2 = d2w(px, py, pz, sqp,
                                     sx[qa], sy[qa], sz[qa], sw[qa]);  // PINNED
                const int o = atomicAdd(&cnt[pt], 1);
                if (o < CAP) list[pt * CAP + o] = make_float2(d2, __int_as_float(q));
            }
        }
    }
    __syncthreads();

    // ---- final: rank-by-counting, all 512 threads (32 slots x 16 points) ----
    {
        const int p2 = t >> 5;               // point 0..15
        const int sl = t & 31;               // slot 0..31
        const int n  = min(cnt[p2], CAP);
        const uint base = (uint)(b * NPTS + chunk * PPB + p2) * (uint)NNBR;
        for (int e = sl; e < n; e += 32) {
            const float2 ve = list[p2 * CAP + e];
            const int ie = __float_as_int(ve.y);
            int r = 0;
            for (int f = 0; f < n; ++f) {
                const float2 vf = list[p2 * CAP + f];
                const bool lt = (vf.x < ve.x) ||
                                (vf.x == ve.x && __float_as_int(vf.y) < ie);
                r += lt ? 1 : 0;
            }
            if (r < NNBR) nbr[base + r] = (ushort)ie;
        }
    }
}

// ---------------------------------------------------------------------------
// MLP + neighbor mean (one wave per point, lane = output channel) with the
// v0 passthrough copy folded in (first 48 blocks copy one float4/thread).
// ---------------------------------------------------------------------------
__global__ __launch_bounds__(256) void mlp_kernel(const float* __restrict__ x0,
                                                  const float* __restrict__ v0,
                                                  const float* __restrict__ W,
                                                  const float* __restrict__ bias,
                                                  const ushort* __restrict__ nbr,
                                                  float* __restrict__ out) {
    const int t   = threadIdx.x;
    const int gid = blockIdx.x * 256 + t;
    if (gid < (4 * NPTS * 3) / 4) {                 // 12288 float4 copies
        ((float4*)(out + 4 * NPTS * 64))[gid] = ((const float4*)v0)[gid];
    }

    const int wave = t >> 6;
    const int lane = t & 63;
    const int gp   = blockIdx.x * 4 + wave;         // global point id 0..16383
    const int b    = gp >> 12;
    const int p    = gp & (NPTS - 1);

    const float* Xb = x0 + b * (NPTS * 3);
    const float* Vb = v0 + b * (NPTS * 3);

    float w[12];
#pragma unroll
    for (int k = 0; k < 12; ++k) w[k] = W[k * 64 + lane];
    const float bb = bias[lane];

    const float xi0 = Xb[p * 3 + 0], xi1 = Xb[p * 3 + 1], xi2 = Xb[p * 3 + 2];
    const float vi0 = Vb[p * 3 + 0], vi1 = Vb[p * 3 + 1], vi2 = Vb[p * 3 + 2];

    const float base = bb + w[0] * xi0 + w[1] * xi1 + w[2] * xi2
                          + w[6] * vi0 + w[7] * vi1 + w[8] * vi2;

    __shared__ float nb[4][NNBR][8];
    if (lane < NNBR) {
        const int j = (int)nbr[(uint)gp * NNBR + lane];
        nb[wave][lane][0] = Xb[j * 3 + 0];
        nb[wave][lane][1] = Xb[j * 3 + 1];
        nb[wave][lane][2] = Xb[j * 3 + 2];
        nb[wave][lane][3] = Vb[j * 3 + 0];
        nb[wave][lane][4] = Vb[j * 3 + 1];
        nb[wave][lane][5] = Vb[j * 3 + 2];
    }
    __syncthreads();

    float acc = 0.0f;
#pragma unroll
    for (int n = 0; n < NNBR; ++n) {
        const float h = base + w[3]  * nb[wave][n][0] + w[4]  * nb[wave][n][1]
                             + w[5]  * nb[wave][n][2] + w[9]  * nb[wave][n][3]
                             + w[10] * nb[wave][n][4] + w[11] * nb[wave][n][5];
        acc += fmaxf(h, 0.0f);
    }

    out[(size_t)gp * 64 + lane] = acc * (1.0f / 16.0f);
}

extern "C" void kernel_launch(void* const* d_in, const int* in_sizes, int n_in,
                              void* d_out, int out_size, void* d_ws, size_t ws_size,
                              hipStream_t stream) {
    const float* x0 = (const float*)d_in[0];   // (4, 12288)
    const float* v0 = (const float*)d_in[1];   // (4, 12288)
    const float* W  = (const float*)d_in[2];   // (12, 64)
    const float* bb = (const float*)d_in[3];   // (64,)
    float* out = (float*)d_out;

    ushort* nbr = (ushort*)d_ws;               // 16384 * 16 * 2B = 512 KB

    // 1) fused exact 16-NN: 1024 blocks (4 batches x 256 chunks of 16 points),
    //    512 threads (16 pts x 32 segs).
    knn_kernel<<<1024, 512, 0, stream>>>(x0, nbr);

    // 2) MLP + mean (+ folded v0 copy): 4 points/block, 4096 blocks.
    mlp_kernel<<<4096, 256, 0, stream>>>(x0, v0, W, bb, nbr, out);
}

// Round 17
// 58.500 us; speedup vs baseline: 2.6022x; 1.0449x over previous
//
#include <hip/hip_runtime.h>
#include <hip/hip_bf16.h>
#include <stdint.h>

#define NPTS 4096
#define NNBR 16      // neighbors kept (reference keeps 17 incl. self, drops self)
#define PPB  16      // points per block
#define NSEG 32      // segments (seg = t>>4); each owns 64 cands PER HALF (128 total)
#define HALF 2048    // points staged per half
#define HSEGLEN 64   // candidates per segment per half
#define SEGPAD 68    // 68 % 32 == 4: wave's 4 seg-rows land on distinct bank-quads
#define HSTR 33      // heads stride per point (32 seg-minima + pad)
#define CAP  96      // accepted capacity (rank(tau) ~ 35-45, same as R16 -> proven)
#define TAUM 1.0e-3f // proxy-vs-pinned margin (bound ~4e-5; 25x safety)
#define BIGD 3.4e38f

// ---------------------------------------------------------------------------
// PINNED distance (numpy-order, no contraction) — used for the accepted-list
// d2 values so the selected neighbor set is bitwise-stable. Point coords are
// read from GLOBAL (same f32 bits as staged) so halves can be swapped freely.
// ---------------------------------------------------------------------------
__device__ __forceinline__ float sqnorm(float x, float y, float z) {
    return __fadd_rn(__fadd_rn(__fmul_rn(x, x), __fmul_rn(y, y)), __fmul_rn(z, z));
}
__device__ __forceinline__ float d2w(float px, float py, float pz, float sqp,
                                     float cx, float cy, float cz, float sqq) {
    const float dot = __fadd_rn(__fadd_rn(__fmul_rn(px, cx), __fmul_rn(py, cy)),
                                __fmul_rn(pz, cz));
    return __fsub_rn(__fadd_rn(sqp, sqq), __fadd_rn(dot, dot));
}
// CHEAP monotone proxy for the scans: e = sqq - 2*dot (= d2 - sqp up to ~ulps).
__device__ __forceinline__ float eproxy(float px, float py, float pz,
                                        float cx, float cy, float cz, float sqq) {
    const float dot = __builtin_fmaf(px, cx, __builtin_fmaf(py, cy, __fmul_rn(pz, cz)));
    return __builtin_fmaf(dot, -2.0f, sqq);
}

// generic K-deep min/max ladder over a register array (static unroll only)
#define LADK(AD, K, S)                                            \
    _Pragma("unroll")                                             \
    for (int k_ = 0; k_ < (K); ++k_) {                            \
        const float lo_ = fminf((S), AD[k_]);                     \
        (S) = fmaxf((S), AD[k_]);                                 \
        AD[k_] = lo_;                                             \
    }

// ---------------------------------------------------------------------------
// Fused exact 16-NN, HALF-STAGED for 3 blocks/CU occupancy.
// Block = 512 thr = 16 points x 32 segments, grid = 1024 (1 pt/thread).
// R16 algorithm (proven 57.5us / absmax 0.0546875) with the staging split in
// two 2048-point halves (34.8KB vs 67.6KB): LDS total ~47.5KB -> 3 blocks/CU
// (was 2). Scans run per-half with register-resident state across restages;
// 4 stagings total (re-reads are L2-resident). tau = 17th of the same 32
// full-segment minima; pinned-d2 + rank-by-counting final => identical sets.
// ---------------------------------------------------------------------------
__global__ __launch_bounds__(512, 6) void knn_kernel(const float* __restrict__ x0,
                                                     ushort* __restrict__ nbr) {
    __shared__ float sx[NSEG * SEGPAD], sy[NSEG * SEGPAD],
                     sz[NSEG * SEGPAD], sw[NSEG * SEGPAD];   // 4 x 8,704 B
    __shared__ float2 list[PPB * CAP];                       // 12,288 B
    __shared__ float ttau[PPB];
    __shared__ int   cnt[PPB];

    float* heads = (float*)list;             // alias: dead before extraction

    const int b     = blockIdx.x >> 8;       // 256 chunks per batch
    const int chunk = blockIdx.x & 255;
    const float* Xb = x0 + b * (NPTS * 3);
    const int t = threadIdx.x;

    const int pt = t & 15, seg = t >> 4;     // seg 0..31
    const int p  = chunk * PPB + pt;         // batch-local point id
    const float px = Xb[3 * p + 0];          // own coords from GLOBAL
    const float py = Xb[3 * p + 1];          // (same f32 bits as staged)
    const float pz = Xb[3 * p + 2];
    const float sqp = sqnorm(px, py, pz);
    const int sb = seg * SEGPAD;

    // stage one 2048-point half into LDS (4 pts/thread)
#define STAGE(HB)                                                  \
    for (int i = t; i < HALF; i += 512) {                          \
        const int g = (HB) * HALF + i;                             \
        const int a = (i >> 6) * SEGPAD + (i & 63);                \
        const float x = Xb[3 * g + 0];                             \
        const float y = Xb[3 * g + 1];                             \
        const float z = Xb[3 * g + 2];                             \
        sx[a] = x; sy[a] = y; sz[a] = z; sw[a] = sqnorm(x, y, z);  \
    }

    // per-half min-chain over this thread's 64 candidates (dual chains)
#define SCAN1H(HA, HBCH)                                           \
    for (int j = 0; j < 16; j += 2) {                              \
        const int oa = sb + 4 * j;                                 \
        const int ob = oa + 4;                                     \
        const float4 cxa = *(const float4*)&sx[oa];                \
        const float4 cya = *(const float4*)&sy[oa];                \
        const float4 cza = *(const float4*)&sz[oa];                \
        const float4 cwa = *(const float4*)&sw[oa];                \
        const float4 cxb = *(const float4*)&sx[ob];                \
        const float4 cyb = *(const float4*)&sy[ob];                \
        const float4 czb = *(const float4*)&sz[ob];                \
        const float4 cwb = *(const float4*)&sw[ob];                \
        const float sa0 = eproxy(px, py, pz, cxa.x, cya.x, cza.x, cwa.x); \
        const float sa1 = eproxy(px, py, pz, cxa.y, cya.y, cza.y, cwa.y); \
        const float sa2 = eproxy(px, py, pz, cxa.z, cya.z, cza.z, cwa.z); \
        const float sa3 = eproxy(px, py, pz, cxa.w, cya.w, cza.w, cwa.w); \
        const float sb0 = eproxy(px, py, pz, cxb.x, cyb.x, czb.x, cwb.x); \
        const float sb1 = eproxy(px, py, pz, cxb.y, cyb.y, czb.y, cwb.y); \
        const float sb2 = eproxy(px, py, pz, cxb.z, cyb.z, czb.z, cwb.z); \
        const float sb3 = eproxy(px, py, pz, cxb.w, cyb.w, czb.w, cwb.w); \
        HA   = fminf(HA,   fminf(fminf(sa0, sa1), fminf(sa2, sa3)));      \
        HBCH = fminf(HBCH, fminf(fminf(sb0, sb1), fminf(sb2, sb3)));      \
    }

    // per-half scan2: bitmask accept + extraction with PINNED d2
#define SCAN2H(HB)                                                             \
    for (int w = 0; w < 2; ++w) {                                              \
        uint m = 0;                                                            \
        _Pragma("unroll")                                                      \
        for (int jj = 0; jj < 8; ++jj) {                                       \
            const int o = sb + w * 32 + 4 * jj;                                \
            const float4 cx4 = *(const float4*)&sx[o];                         \
            const float4 cy4 = *(const float4*)&sy[o];                         \
            const float4 cz4 = *(const float4*)&sz[o];                         \
            const float4 cw4 = *(const float4*)&sw[o];                         \
            const float s0 = eproxy(px, py, pz, cx4.x, cy4.x, cz4.x, cw4.x);   \
            const float s1 = eproxy(px, py, pz, cx4.y, cy4.y, cz4.y, cw4.y);   \
            const float s2 = eproxy(px, py, pz, cx4.z, cy4.z, cz4.z, cw4.z);   \
            const float s3 = eproxy(px, py, pz, cx4.w, cy4.w, cz4.w, cw4.w);   \
            m |= (s0 <= tv) ? (1u << (4 * jj + 0)) : 0u;                       \
            m |= (s1 <= tv) ? (1u << (4 * jj + 1)) : 0u;                       \
            m |= (s2 <= tv) ? (1u << (4 * jj + 2)) : 0u;                       \
            m |= (s3 <= tv) ? (1u << (4 * jj + 3)) : 0u;                       \
        }                                                                      \
        while (m) {                                                            \
            const int bpos = __ffs(m) - 1;                                     \
            m &= m - 1;                                                        \
            const int l = seg * HSEGLEN + w * 32 + bpos;                       \
            const int q = (HB) * HALF + l;   /* batch-local cand id */         \
            if (q != p) {                                                      \
                const int qa = (l >> 6) * SEGPAD + (l & 63);                   \
                const float d2 = d2w(px, py, pz, sqp,                          \
                                     sx[qa], sy[qa], sz[qa], sw[qa]);          \
                const int o2 = atomicAdd(&cnt[pt], 1);                         \
                if (o2 < CAP) list[pt * CAP + o2] = make_float2(d2, __int_as_float(q)); \
            }                                                                  \
        }                                                                      \
    }

    // ---- phase A: stage half0, scan1 on it ----
    STAGE(0)
    if (t < PPB) cnt[t] = 0;
    __syncthreads();

    float ha = BIGD, hb = BIGD;
    SCAN1H(ha, hb)
    __syncthreads();                         // done reading half0

    // ---- phase B: stage half1, finish scan1, write seg-minima ----
    STAGE(1)
    __syncthreads();
    SCAN1H(ha, hb)
    heads[pt * HSTR + seg] = fminf(ha, hb);  // min over all 128 cands
    __syncthreads();

    // ---- tau: 1 thr/pt, LAD17 over the 32 seg-minima (rotated reads) ----
    if (t < PPB) {
        float ad[17];
#pragma unroll
        for (int k = 0; k < 17; ++k) ad[k] = BIGD;
        const float* src = heads + t * HSTR;
        for (int e = 0; e < 32; ++e) {
            float s = src[(e + t) & 31];
            LADK(ad, 17, s)
        }
        ttau[t] = ad[16];                    // 17th-smallest seg-minimum
    }
    __syncthreads();                         // heads dead; list reuses the space

    // ---- phase C: scan2 on resident half1, then restage half0 and scan2 ----
    const float tv = ttau[pt] + TAUM;
    SCAN2H(1)
    __syncthreads();                         // done reading half1
    STAGE(0)
    __syncthreads();
    SCAN2H(0)
    __syncthreads();

    // ---- final: rank-by-counting, all 512 threads (32 slots x 16 points) ----
    {
        const int p2 = t >> 5;               // point 0..15
        const int sl = t & 31;               // slot 0..31
        const int n  = min(cnt[p2], CAP);
        const uint base = (uint)(b * NPTS + chunk * PPB + p2) * (uint)NNBR;
        for (int e = sl; e < n; e += 32) {
            const float2 ve = list[p2 * CAP + e];
            const int ie = __float_as_int(ve.y);
            int r = 0;
            for (int f = 0; f < n; ++f) {
                const float2 vf = list[p2 * CAP + f];
                const bool lt = (vf.x < ve.x) ||
                                (vf.x == ve.x && __float_as_int(vf.y) < ie);
                r += lt ? 1 : 0;
            }
            if (r < NNBR) nbr[base + r] = (ushort)ie;
        }
    }
#undef STAGE
#undef SCAN1H
#undef SCAN2H
}

// ---------------------------------------------------------------------------
// MLP + neighbor mean (one wave per point, lane = output channel) with the
// v0 passthrough copy folded in (first 48 blocks copy one float4/thread).
// ---------------------------------------------------------------------------
__global__ __launch_bounds__(256) void mlp_kernel(const float* __restrict__ x0,
                                                  const float* __restrict__ v0,
                                                  const float* __restrict__ W,
                                                  const float* __restrict__ bias,
                                                  const ushort* __restrict__ nbr,
                                                  float* __restrict__ out) {
    const int t   = threadIdx.x;
    const int gid = blockIdx.x * 256 + t;
    if (gid < (4 * NPTS * 3) / 4) {                 // 12288 float4 copies
        ((float4*)(out + 4 * NPTS * 64))[gid] = ((const float4*)v0)[gid];
    }

    const int wave = t >> 6;
    const int lane = t & 63;
    const int gp   = blockIdx.x * 4 + wave;         // global point id 0..16383
    const int b    = gp >> 12;
    const int p    = gp & (NPTS - 1);

    const float* Xb = x0 + b * (NPTS * 3);
    const float* Vb = v0 + b * (NPTS * 3);

    float w[12];
#pragma unroll
    for (int k = 0; k < 12; ++k) w[k] = W[k * 64 + lane];
    const float bb = bias[lane];

    const float xi0 = Xb[p * 3 + 0], xi1 = Xb[p * 3 + 1], xi2 = Xb[p * 3 + 2];
    const float vi0 = Vb[p * 3 + 0], vi1 = Vb[p * 3 + 1], vi2 = Vb[p * 3 + 2];

    const float base = bb + w[0] * xi0 + w[1] * xi1 + w[2] * xi2
                          + w[6] * vi0 + w[7] * vi1 + w[8] * vi2;

    __shared__ float nb[4][NNBR][8];
    if (lane < NNBR) {
        const int j = (int)nbr[(uint)gp * NNBR + lane];
        nb[wave][lane][0] = Xb[j * 3 + 0];
        nb[wave][lane][1] = Xb[j * 3 + 1];
        nb[wave][lane][2] = Xb[j * 3 + 2];
        nb[wave][lane][3] = Vb[j * 3 + 0];
        nb[wave][lane][4] = Vb[j * 3 + 1];
        nb[wave][lane][5] = Vb[j * 3 + 2];
    }
    __syncthreads();

    float acc = 0.0f;
#pragma unroll
    for (int n = 0; n < NNBR; ++n) {
        const float h = base + w[3]  * nb[wave][n][0] + w[4]  * nb[wave][n][1]
                             + w[5]  * nb[wave][n][2] + w[9]  * nb[wave][n][3]
                             + w[10] * nb[wave][n][4] + w[11] * nb[wave][n][5];
        acc += fmaxf(h, 0.0f);
    }

    out[(size_t)gp * 64 + lane] = acc * (1.0f / 16.0f);
}

extern "C" void kernel_launch(void* const* d_in, const int* in_sizes, int n_in,
                              void* d_out, int out_size, void* d_ws, size_t ws_size,
                              hipStream_t stream) {
    const float* x0 = (const float*)d_in[0];   // (4, 12288)
    const float* v0 = (const float*)d_in[1];   // (4, 12288)
    const float* W  = (const float*)d_in[2];   // (12, 64)
    const float* bb = (const float*)d_in[3];   // (64,)
    float* out = (float*)d_out;

    ushort* nbr = (ushort*)d_ws;               // 16384 * 16 * 2B = 512 KB

    // 1) fused exact 16-NN: 1024 blocks (4 batches x 256 chunks of 16 points),
    //    512 threads (16 pts x 32 segs), half-staged for 3 blocks/CU.
    knn_kernel<<<1024, 512, 0, stream>>>(x0, nbr);

    // 2) MLP + mean (+ folded v0 copy): 4 points/block, 4096 blocks.
    mlp_kernel<<<4096, 256, 0, stream>>>(x0, v0, W, bb, nbr, out);
}